// Round 8
// baseline (6198.117 us; speedup 1.0000x reference)
//
#include <hip/hip_runtime.h>

// Problem dims
#define T_ 512
#define B_ 64
#define E_ 256
#define H_ 256
#define K_ 21

typedef short          s16x8 __attribute__((ext_vector_type(8)));
typedef unsigned short u16x4 __attribute__((ext_vector_type(4)));
typedef float          f32x4 __attribute__((ext_vector_type(4)));
typedef unsigned long long u64x2 __attribute__((ext_vector_type(2)));

// ---- module-scope device scratch (d_out is float32; d_ws unused) ----
__device__ __attribute__((aligned(16))) unsigned short g_hs[T_ * B_ * 2 * H_];  // [T][B][2H] bf16 bits
// 4-deep h exchange ring: [dir][buf(step&3)][B][H]; values class-tagged via bit14
__device__ __attribute__((aligned(16))) unsigned short g_hbuf[2 * 4 * B_ * H_];
__device__ __attribute__((aligned(16))) float    g_em[T_ * B_ * K_];            // [T][B][K] f32
__device__ __attribute__((aligned(16))) unsigned short g_wpk[2048 * 256];       // wih bf16 packed [f;b][256]
__device__ __attribute__((aligned(16))) unsigned short g_hpk[2048 * 256];       // whh bf16 packed [f;b][256]
// pre[t][n_tile(128)][m_tile(4)][lane(64)][4] f32 -- MFMA C-fragment layout (268 MB)
__device__ __attribute__((aligned(16))) float g_pre[(size_t)T_ * 128 * 4 * 64 * 4];
// ---- diagnostics: every failure mode -> distinct loss-slot value ----
__device__ int   g_marker;
__device__ int   g_done_pre;    // expect 512
__device__ int   g_done_lstm;   // expect 32
__device__ int   g_done_dec;    // expect 128
__device__ int   g_timeout;
__device__ float g_sum;

#define CLASS_MASK 0x4000400040004000ULL

__device__ __forceinline__ f32x4 mfma16(s16x8 a, s16x8 b, f32x4 c) {
  return __builtin_amdgcn_mfma_f32_16x16x32_bf16(a, b, c, 0, 0, 0);
}

// f32 -> bf16 bits, round-to-nearest-even (finite inputs only)
__device__ __forceinline__ unsigned short f2b(float f) {
  unsigned u = __float_as_uint(f);
  u = (u + 0x7fffu + ((u >> 16) & 1u)) >> 16;
  return (unsigned short)u;
}

__device__ __forceinline__ s16x8 cvt8(const float* p) {
  s16x8 v;
#pragma unroll
  for (int j = 0; j < 8; ++j) v[j] = (short)f2b(p[j]);
  return v;
}

// assemble an MFMA A-fragment from two 64-bit raw words
__device__ __forceinline__ s16x8 frag2(unsigned long long a, unsigned long long b) {
  u64x2 t; t[0] = a; t[1] = b;
  return __builtin_bit_cast(s16x8, t);
}

// pre-fragment address for (time t, dir, slice s, wave wn/wm, lane, ni, mi)
__device__ __forceinline__ const f32x4* pre_tile(int t, int dir, int s, int wn, int wm,
                                                 int lane, int ni, int mi) {
  size_t idx = ((((size_t)t * 128 + dir * 64 + (2 * wn + ni) * 16 + s) * 4)
                + (wm * 2 + mi)) * 64 + lane;
  return (const f32x4*)(g_pre + idx * 4);
}

// ---------------- K0: init h ring to class-1 sentinel, zero diagnostics ----------------
__global__ void k_zero() {
  int i = blockIdx.x * 256 + threadIdx.x;   // 65536 threads == exactly the u64 count
  ((unsigned long long*)g_hbuf)[i] = CLASS_MASK;  // bit14=1 everywhere: class 1
  if (i == 0) {
    g_marker = 1;
    g_done_pre = 0;
    g_done_lstm = 0;
    g_done_dec = 0;
    g_timeout = 0;
    g_sum = 0.f;
  }
}

// ---------------- Kp: pack wih/whh to bf16, fragment-friendly row-major ----------------
__global__ __launch_bounds__(256) void k_prep(
    const float* __restrict__ wih_f, const float* __restrict__ wih_b,
    const float* __restrict__ whh_f, const float* __restrict__ whh_b) {
  const int r = blockIdx.x;     // 0..2047
  const int c = threadIdx.x;    // 0..255
  const int rr = r & 1023;
  const float* wi = (r < 1024) ? wih_f : wih_b;
  const float* wh = (r < 1024) ? whh_f : whh_b;
  g_wpk[(size_t)r * 256 + c] = f2b(wi[(size_t)rr * E_ + c]);
  g_hpk[(size_t)r * 256 + c] = f2b(wh[(size_t)rr * H_ + c]);
}

// ---------------- Kq: input projection pre = xe @ wih^T, all t in parallel ----------
__global__ __launch_bounds__(256) void k_pre(const int* __restrict__ x,
                                             const float* __restrict__ emb) {
  const int t = blockIdx.x;
  const int tid = threadIdx.x;
  const int lane = tid & 63;
  const int wv = tid >> 6;
  const int wm = wv & 1;
  const int wn = wv >> 1;
  const int l15 = lane & 15;
  const int l4 = lane >> 4;
  const int b0 = wm * 32 + l15;
  const int b1 = b0 + 16;

  s16x8 a0[8], a1[8];
  {
    const float* e0 = emb + (size_t)x[b0 * T_ + t] * E_;
    const float* e1 = emb + (size_t)x[b1 * T_ + t] * E_;
#pragma unroll
    for (int kc = 0; kc < 8; ++kc) {
      a0[kc] = cvt8(e0 + kc * 32 + l4 * 8);
      a1[kc] = cvt8(e1 + kc * 32 + l4 * 8);
    }
  }

  for (int ntl = 0; ntl < 64; ++ntl) {
    const int nt = wn * 64 + ntl;      // n_tile 0..127 (f gates 0..63, b gates 64..127)
    s16x8 bf[8];
#pragma unroll
    for (int kc = 0; kc < 8; ++kc)
      bf[kc] = *(const s16x8*)(g_wpk + (size_t)(nt * 16 + l15) * 256 + kc * 32 + l4 * 8);
    f32x4 c0 = {0, 0, 0, 0}, c1 = {0, 0, 0, 0};
#pragma unroll
    for (int kc = 0; kc < 8; ++kc) {
      c0 = mfma16(a0[kc], bf[kc], c0);
      c1 = mfma16(a1[kc], bf[kc], c1);
    }
    *(f32x4*)(g_pre + ((((size_t)t * 128 + nt) * 4 + wm * 2 + 0) * 64 + lane) * 4) = c0;
    *(f32x4*)(g_pre + ((((size_t)t * 128 + nt) * 4 + wm * 2 + 1) * 64 + lane) * 4) = c1;
  }
  if (tid == 0) atomicAdd(&g_done_pre, 1);
}

// One LSTM time step, drain-free ordering:
//   1) issue poll loads for h(step-1)            (oldest vmem ops of the step)
//   2) deferred publish stores of h(step-1)      (newer than polls: not drained by them)
//   3) prefetch pre(step+1)                      (newest: stays in flight across detect)
//   4) wait/check (own-slice pieces masked; own data comes from LDS hShare)
//   5) MFMA -> scatter -> [lgkmcnt+s_barrier, NO vmcnt drain] -> gates -> hShare write
//      -> [lgkmcnt+s_barrier]
// In-order vmcnt retirement means waiting for the polls never waits for the newer
// stores/prefetch -- the per-step ~1.4us drain tax of R4/R5 disappears.
__device__ __forceinline__ void lstm_step(
    int step, int dir, int s, int wv, int lane, int wm, int wn,
    int l15, int l4, int em_m, int em_jg,
    unsigned short* hb4,
    const s16x8 (&bfr)[2][8], const float (&bq)[4][4], float (&cst)[4],
    float* G,
    unsigned long long* hSprev, unsigned long long* hScur,
    f32x4 (&preC)[4], f32x4 (&preN)[4],
    u16x4& hvP, unsigned long long& evP)
{
  const int am0 = wm * 32 + l15;
  const int am1 = am0 + 16;
  const unsigned long long M = CLASS_MASK;
  const int kcO = s >> 1;                    // kc block holding own-slice pieces
  const bool own = ((l4 >> 1) == (s & 1));   // lanes whose A-pieces include own slice

  unsigned long long r0[16], r1[16];
  const unsigned long long* h0q = nullptr;
  const unsigned long long* h1q = nullptr;
  unsigned long long want = 0ull;

  if (step == 0) {
#pragma unroll
    for (int i = 0; i < 16; ++i) { r0[i] = 0ull; r1[i] = 0ull; }   // h(-1) = 0
  } else {
    const int rbuf = (step - 1) & 3;
    want = (((step - 1) >> 2) & 1) ? M : 0ull;
    const unsigned long long* hq = (const unsigned long long*)(hb4 + rbuf * (B_ * H_));
    h0q = hq + am0 * (H_ / 4) + l4 * 2;
    h1q = hq + am1 * (H_ / 4) + l4 * 2;
    // (1) round-0 poll loads -- FIRST vmem ops of this step
#pragma unroll
    for (int kc = 0; kc < 8; ++kc) {
      r0[2*kc]   = __hip_atomic_load(h0q + kc*8,   __ATOMIC_RELAXED, __HIP_MEMORY_SCOPE_AGENT);
      r0[2*kc+1] = __hip_atomic_load(h0q + kc*8+1, __ATOMIC_RELAXED, __HIP_MEMORY_SCOPE_AGENT);
      r1[2*kc]   = __hip_atomic_load(h1q + kc*8,   __ATOMIC_RELAXED, __HIP_MEMORY_SCOPE_AGENT);
      r1[2*kc+1] = __hip_atomic_load(h1q + kc*8+1, __ATOMIC_RELAXED, __HIP_MEMORY_SCOPE_AGENT);
    }
    // (2) deferred publish of h(step-1): ring store (peer-critical) + persistent store
    {
      const int wbP = (step - 1) & 3;
      unsigned short* hrow = hb4 + wbP * (B_ * H_) + em_m * H_ + s * 16 + em_jg * 4;
      __hip_atomic_store((unsigned long long*)hrow, evP,
                         __ATOMIC_RELAXED, __HIP_MEMORY_SCOPE_AGENT);
      const int tP = dir ? (T_ - step) : (step - 1);
      unsigned short* hsro = g_hs + ((size_t)tP * B_ + em_m) * (2 * H_) + dir * H_ + s * 16 + em_jg * 4;
      *(u16x4*)hsro = hvP;
    }
  }

  // (3) prefetch pre(step+1): newest vmem -- stays in flight across the detect wait
  if (step + 1 < T_) {
    const int tn = dir ? (T_ - 2 - step) : (step + 1);
    preN[0] = *pre_tile(tn, dir, s, wn, wm, lane, 0, 0);
    preN[1] = *pre_tile(tn, dir, s, wn, wm, lane, 1, 0);
    preN[2] = *pre_tile(tn, dir, s, wn, wm, lane, 0, 1);
    preN[3] = *pre_tile(tn, dir, s, wn, wm, lane, 1, 1);
  }

  if (step > 0) {
    // (4) wait: freshness via bit14 class; own-slice pieces masked (come from LDS)
    int it = 0;
    for (;;) {
      unsigned long long bad = 0ull;
#pragma unroll
      for (int kc = 0; kc < 8; ++kc) {
        unsigned long long a = r0[2*kc], b = r0[2*kc+1];
        unsigned long long c = r1[2*kc], d = r1[2*kc+1];
        if (own && kc == kcO) { a = want; b = want; c = want; d = want; }
        bad |= (a & M) ^ want;  bad |= (b & M) ^ want;
        bad |= (c & M) ^ want;  bad |= (d & M) ^ want;
      }
      if (__all(bad == 0ull)) break;
      __builtin_amdgcn_s_sleep(1);
      if (++it > (1 << 13)) { if (lane == 0) atomicAdd(&g_timeout, 1); break; }
#pragma unroll
      for (int kc = 0; kc < 8; ++kc) {
        r0[2*kc]   = __hip_atomic_load(h0q + kc*8,   __ATOMIC_RELAXED, __HIP_MEMORY_SCOPE_AGENT);
        r0[2*kc+1] = __hip_atomic_load(h0q + kc*8+1, __ATOMIC_RELAXED, __HIP_MEMORY_SCOPE_AGENT);
        r1[2*kc]   = __hip_atomic_load(h1q + kc*8,   __ATOMIC_RELAXED, __HIP_MEMORY_SCOPE_AGENT);
        r1[2*kc+1] = __hip_atomic_load(h1q + kc*8+1, __ATOMIC_RELAXED, __HIP_MEMORY_SCOPE_AGENT);
      }
    }
    if (want) {          // lossless decode (own pieces overwritten below anyway)
#pragma unroll
      for (int i = 0; i < 16; ++i) { r0[i] ^= M; r1[i] ^= M; }
    }
    // substitute own-slice pieces from hShare (exact same bf16 bits as memory path)
    {
      const int pi = (l4 & 1) * 2;
      unsigned long long sA0 = hSprev[am0 * 4 + pi], sA1 = hSprev[am0 * 4 + pi + 1];
      unsigned long long sB0 = hSprev[am1 * 4 + pi], sB1 = hSprev[am1 * 4 + pi + 1];
#pragma unroll
      for (int kc = 0; kc < 8; ++kc) {
        bool o = own && (kc == kcO);
        r0[2*kc]   = o ? sA0 : r0[2*kc];
        r0[2*kc+1] = o ? sA1 : r0[2*kc+1];
        r1[2*kc]   = o ? sB0 : r1[2*kc];
        r1[2*kc+1] = o ? sB1 : r1[2*kc+1];
      }
    }
  }

  // acc init = precomputed xe@wih^T partials; then h @ whh^T (same order as R4/R5)
  f32x4 acc00 = preC[0], acc01 = preC[1], acc10 = preC[2], acc11 = preC[3];
#pragma unroll
  for (int kc = 0; kc < 8; ++kc) {
    s16x8 a0 = frag2(r0[2 * kc], r0[2 * kc + 1]);
    s16x8 a1 = frag2(r1[2 * kc], r1[2 * kc + 1]);
    acc00 = mfma16(a0, bfr[0][kc], acc00);
    acc01 = mfma16(a0, bfr[1][kc], acc01);
    acc10 = mfma16(a1, bfr[0][kc], acc10);
    acc11 = mfma16(a1, bfr[1][kc], acc11);
  }

  // scatter to LDS: G[m][n]; C/D layout col=lane&15, row=(lane>>4)*4+r
#pragma unroll
  for (int mi = 0; mi < 2; ++mi)
#pragma unroll
    for (int ni = 0; ni < 2; ++ni) {
      f32x4 a = (mi == 0) ? (ni == 0 ? acc00 : acc01) : (ni == 0 ? acc10 : acc11);
#pragma unroll
      for (int r = 0; r < 4; ++r) {
        int m = wm * 32 + mi * 16 + l4 * 4 + r;
        int n = (2 * wn + ni) * 16 + l15;
        G[m * 65 + n] = a[r];
      }
    }
  // barrier WITHOUT vmcnt drain: stores/prefetch stay in flight
  asm volatile("s_waitcnt lgkmcnt(0)\n\ts_barrier" ::: "memory");

  // gates + state update (values kept in regs; published at next step's top)
  u16x4 hv;
#pragma unroll
  for (int p = 0; p < 4; ++p) {
    int j = em_jg * 4 + p;
    float gi = G[em_m * 65 +  0 + j] + bq[0][p];
    float gf = G[em_m * 65 + 16 + j] + bq[1][p];
    float gg = G[em_m * 65 + 32 + j] + bq[2][p];
    float go = G[em_m * 65 + 48 + j] + bq[3][p];
    float ii = 1.f / (1.f + __expf(-gi));
    float ff = 1.f / (1.f + __expf(-gf));
    float gt = 1.f - 2.f / (__expf(2.f * gg) + 1.f);
    float oo = 1.f / (1.f + __expf(-go));
    float c = ff * cst[p] + ii * gt;
    cst[p] = c;
    float h = oo * (1.f - 2.f / (__expf(2.f * c) + 1.f));
    hv[p] = f2b(h);   // |h| < 1: bit14 always 0
  }
  // own-slice share for next step's A-build (raw bits, class-free)
  hScur[em_m * 4 + em_jg] = __builtin_bit_cast(unsigned long long, hv);
  unsigned long long ev = __builtin_bit_cast(unsigned long long, hv);
  if ((step >> 2) & 1) ev ^= M;
  hvP = hv;
  evP = ev;
  // barrier so every wave's hShare write is visible before next step's reads
  asm volatile("s_waitcnt lgkmcnt(0)\n\ts_barrier" ::: "memory");
}

// ---------------- K1: biLSTM recurrence (h @ whh^T only; pre from g_pre) ----------
// 32 WGs: dir = wg&1, slice s = wg>>1. 4 waves. Data-as-flag sync via MALL with
// drain-free issue ordering (see lstm_step). 4-buffer ring deadlock-free: publishing
// h(w-1) at step w requires having validated all h(w-2), which implies every WG
// reached step w-1; overwrite of buf (w-1)&3 happens >= 4 steps after its readers.
__global__ __launch_bounds__(256, 1) void k_lstm(
    const float* __restrict__ b_f, const float* __restrict__ b_b)
{
  const int wg  = blockIdx.x;
  const int dir = wg & 1;
  const int s   = wg >> 1;
  const int tid = threadIdx.x;
  const int lane = tid & 63;
  const int wv  = tid >> 6;      // 0..3
  const int wm  = wv & 1;        // M half (batches wm*32..+31)
  const int wn  = wv >> 1;       // N half (gate-rows wn*32..+31)
  const int l15 = lane & 15;
  const int l4  = lane >> 4;

  const float* bias = dir ? b_b : b_f;
  unsigned short* hb4 = g_hbuf + (size_t)dir * (4 * B_ * H_);

  // stationary whh B-fragments from packed bf16: K = 256 (h only)
  s16x8 bfr[2][8];
#pragma unroll
  for (int ni = 0; ni < 2; ++ni) {
    const int nt = dir * 64 + (2 * wn + ni) * 16 + s;     // global n_tile
    const unsigned short* wr = g_hpk + (size_t)(nt * 16 + l15) * 256;
#pragma unroll
    for (int kc = 0; kc < 8; ++kc)
      bfr[ni][kc] = *(const s16x8*)(wr + kc * 32 + l4 * 8);
  }

  // epilogue mapping: thread -> (batch em_m, 4 units em_jg*4..+3)
  const int em_m  = tid >> 2;
  const int em_jg = tid & 3;
  float bq[4][4];
#pragma unroll
  for (int q = 0; q < 4; ++q)
#pragma unroll
    for (int p = 0; p < 4; ++p) bq[q][p] = bias[q * H_ + s * 16 + em_jg * 4 + p];
  float cst[4] = {0.f, 0.f, 0.f, 0.f};

  __shared__ float Ga[64 * 65];
  __shared__ float Gb[64 * 65];
  __shared__ unsigned long long hSa[64 * 4];   // own-slice share, even steps
  __shared__ unsigned long long hSb[64 * 4];   // own-slice share, odd steps

  // prologue: pre fragments for step 0 into buffer A
  f32x4 preA[4], preB[4];
  {
    const int t0 = dir ? (T_ - 1) : 0;
    preA[0] = *pre_tile(t0, dir, s, wn, wm, lane, 0, 0);
    preA[1] = *pre_tile(t0, dir, s, wn, wm, lane, 1, 0);
    preA[2] = *pre_tile(t0, dir, s, wn, wm, lane, 0, 1);
    preA[3] = *pre_tile(t0, dir, s, wn, wm, lane, 1, 1);
  }

  u16x4 hvP = {0, 0, 0, 0};
  unsigned long long evP = 0ull;

  // T_ = 512 even: explicit 2-step unroll keeps pre/G/hShare statically named
  for (int sp = 0; sp < T_; sp += 2) {
    lstm_step(sp,     dir, s, wv, lane, wm, wn, l15, l4, em_m, em_jg,
              hb4, bfr, bq, cst, Ga, hSb, hSa, preA, preB, hvP, evP);
    lstm_step(sp + 1, dir, s, wv, lane, wm, wn, l15, l4, em_m, em_jg,
              hb4, bfr, bq, cst, Gb, hSa, hSb, preB, preA, hvP, evP);
  }

  // final persistent store for step T-1 (ring store unneeded: nobody polls it)
  {
    const int tl = dir ? 0 : (T_ - 1);
    unsigned short* hsro = g_hs + ((size_t)tl * B_ + em_m) * (2 * H_) + dir * H_ + s * 16 + em_jg * 4;
    *(u16x4*)hsro = hvP;
  }

  __syncthreads();
  if (tid == 0) atomicAdd(&g_done_lstm, 1);
}

// ---------------- K2: emissions em[t][b][k] = hs @ wc^T + bc (MFMA, N padded to 32) ----
__global__ __launch_bounds__(256) void k_em(const float* __restrict__ wc,
                                            const float* __restrict__ bc) {
  const int tid = threadIdx.x;
  const int lane = tid & 63;
  const int wv = tid >> 6;
  const int l15 = lane & 15;
  const int l4 = lane >> 4;
  const int row0 = blockIdx.x * 64 + wv * 16;   // (t*64+b) row block

  s16x8 bfr[2][16];
#pragma unroll
  for (int ni = 0; ni < 2; ++ni) {
    int n = ni * 16 + l15;
#pragma unroll
    for (int kc = 0; kc < 16; ++kc) {
      s16x8 v;
      if (n < K_) {
        v = cvt8(wc + (size_t)n * (2 * H_) + kc * 32 + l4 * 8);
      } else {
#pragma unroll
        for (int jj = 0; jj < 8; ++jj) v[jj] = 0;
      }
      bfr[ni][kc] = v;
    }
  }

  f32x4 acc0 = {0,0,0,0}, acc1 = {0,0,0,0};
  const unsigned short* arow = g_hs + (size_t)(row0 + l15) * (2 * H_) + l4 * 8;
#pragma unroll
  for (int kc = 0; kc < 16; ++kc) {
    s16x8 a = *(const s16x8*)(arow + kc * 32);
    acc0 = mfma16(a, bfr[0][kc], acc0);
    acc1 = mfma16(a, bfr[1][kc], acc1);
  }
#pragma unroll
  for (int r = 0; r < 4; ++r) {
    int m = l4 * 4 + r;
    g_em[(size_t)(row0 + m) * K_ + l15] = acc0[r] + bc[l15];       // n0 = l15 < 16 < K
    int n1 = 16 + l15;
    if (n1 < K_) g_em[(size_t)(row0 + m) * K_ + n1] = acc1[r] + bc[n1];
  }
}

// ---------------- K3: decode. blocks 0..63: Viterbi tags; 64..127: CRF llh ----------------
__global__ void k_decode(const int* __restrict__ y,
                         const float* __restrict__ start, const float* __restrict__ endw,
                         const float* __restrict__ trans,
                         float* __restrict__ out_tags) {
  const int id = blockIdx.x;
  const int k = threadIdx.x;   // 64 threads = 1 wave
  const float* em = g_em;
  __shared__ float tr[K_ * K_];
  __shared__ float sc[K_];
  __shared__ unsigned char bp[T_][K_];
  __shared__ short tags[T_];
  __shared__ float zsh;

  for (int i = k; i < K_ * K_; i += 64) tr[i] = trans[i];
  __syncthreads();

  if (id < B_) {
    // ---- Viterbi (argmax ties -> first index, matching jnp.argmax) ----
    const int b = id;
    float score = 0.f;
    if (k < K_) score = start[k] + em[(size_t)b * K_ + k];
    __syncthreads();
    for (int t = 1; t < T_; ++t) {
      if (k < K_) sc[k] = score;
      __syncthreads();
      if (k < K_) {
        float e = em[(size_t)(t * B_ + b) * K_ + k];
        float best = -1e30f; int bi = 0;
        for (int k1 = 0; k1 < K_; ++k1) {
          float v = sc[k1] + tr[k1 * K_ + k];
          if (v > best) { best = v; bi = k1; }
        }
        score = best + e;
        bp[t][k] = (unsigned char)bi;
      }
      __syncthreads();
    }
    if (k < K_) sc[k] = score + endw[k];
    __syncthreads();
    if (k == 0) {
      float best = -1e30f; int bi = 0;
      for (int k1 = 0; k1 < K_; ++k1) if (sc[k1] > best) { best = sc[k1]; bi = k1; }
      short tag = (short)bi;
      tags[T_ - 1] = tag;
      for (int t = T_ - 1; t > 0; --t) { tag = (short)bp[t][tag]; tags[t - 1] = tag; }
    }
    __syncthreads();
    // OUTPUT IS FLOAT32 (reference outputs are int32/f32, not bf16)
    for (int t = k; t < T_; t += 64) out_tags[(size_t)b * T_ + t] = (float)tags[t];
    __syncthreads();
    if (k == 0) atomicAdd(&g_done_dec, 1);
  } else {
    // ---- CRF log-likelihood ----
    const int b = id - B_;
    float al = 0.f;
    if (k < K_) al = start[k] + em[(size_t)b * K_ + k];
    __syncthreads();
    for (int t = 1; t < T_; ++t) {
      if (k < K_) sc[k] = al;
      __syncthreads();
      if (k < K_) {
        float e = em[(size_t)(t * B_ + b) * K_ + k];
        float m = -1e30f;
        for (int k1 = 0; k1 < K_; ++k1) m = fmaxf(m, sc[k1] + tr[k1 * K_ + k]);
        float ssum = 0.f;
        for (int k1 = 0; k1 < K_; ++k1) ssum += __expf(sc[k1] + tr[k1 * K_ + k] - m);
        al = m + __logf(ssum) + e;
      }
      __syncthreads();
    }
    if (k < K_) sc[k] = al + endw[k];
    __syncthreads();
    if (k == 0) {
      float m = -1e30f;
      for (int k1 = 0; k1 < K_; ++k1) m = fmaxf(m, sc[k1]);
      float ssum = 0.f;
      for (int k1 = 0; k1 < K_; ++k1) ssum += __expf(sc[k1] - m);
      zsh = m + __logf(ssum);
    }
    __syncthreads();
    const int* yb = y + b * T_;
    float local = 0.f;
    for (int t = k; t < T_; t += 64) {
      if (t >= 1) {
        int y1 = yb[t], y0 = yb[t - 1];
        local += tr[y0 * K_ + y1] + em[(size_t)(t * B_ + b) * K_ + y1];
      }
    }
    for (int off = 32; off > 0; off >>= 1) local += __shfl_down(local, off, 64);
    if (k == 0) {
      int y0 = yb[0], yl = yb[T_ - 1];
      float num = local + start[y0] + em[(size_t)b * K_ + y0] + endw[yl];
      atomicAdd(&g_sum, (num - zsh) * (1.0f / 64.0f));
      atomicAdd(&g_done_dec, 1);
    }
  }
}

// ---------------- K4: finalize; encode pipeline state into the float loss slot ----------
// error map (vs ref ~ -1560): pass | -2600=timeout | -2800=sum~0 | -3000-32d=lstm
// incomplete | -6000-32d=decode incomplete | -9000-d=pre incomplete | -20000=k_zero missing
__global__ void k_fin(float* __restrict__ out) {
  float v;
  if (g_marker != 1)             v = -20000.f;
  else if (g_done_pre < 512)     v = -9000.f - (float)g_done_pre;
  else if (g_done_lstm < 32)     v = -3000.f - 32.f * (float)g_done_lstm;
  else if (g_done_dec < 128)     v = -6000.f - 32.f * (float)g_done_dec;
  else if (g_timeout != 0)       v = -2600.f;
  else if (fabsf(g_sum) <= 0.5f) v = -2800.f;
  else                           v = g_sum;
  out[0] = v;
}

extern "C" void kernel_launch(void* const* d_in, const int* in_sizes, int n_in,
                              void* d_out, int out_size, void* d_ws, size_t ws_size,
                              hipStream_t stream) {
  const int*   x     = (const int*)d_in[0];
  const int*   y     = (const int*)d_in[1];
  // d_in[2] = masks: all-true by construction -> unused
  const float* emb   = (const float*)d_in[3];
  const float* wih_f = (const float*)d_in[4];
  const float* whh_f = (const float*)d_in[5];
  const float* b_f   = (const float*)d_in[6];
  const float* wih_b = (const float*)d_in[7];
  const float* whh_b = (const float*)d_in[8];
  const float* b_b   = (const float*)d_in[9];
  const float* wc    = (const float*)d_in[10];
  const float* bc    = (const float*)d_in[11];
  const float* start = (const float*)d_in[12];
  const float* endw  = (const float*)d_in[13];
  const float* trans = (const float*)d_in[14];

  float* out_f = (float*)d_out;   // float32: tags [0..B*T), loss at [B*T]

  k_zero<<<256, 256, 0, stream>>>();
  k_prep<<<2048, 256, 0, stream>>>(wih_f, wih_b, whh_f, whh_b);
  k_pre<<<T_, 256, 0, stream>>>(x, emb);
  k_lstm<<<32, 256, 0, stream>>>(b_f, b_b);
  k_em<<<(T_ * B_) / 64, 256, 0, stream>>>(wc, bc);
  k_decode<<<128, 64, 0, stream>>>(y, start, endw, trans, out_f);
  k_fin<<<1, 1, 0, stream>>>(out_f + (size_t)B_ * T_);
}

// Round 11
// 3870.797 us; speedup vs baseline: 1.6013x; 1.6013x over previous
//
#include <hip/hip_runtime.h>

// Problem dims
#define T_ 512
#define B_ 64
#define E_ 256
#define H_ 256
#define K_ 21

typedef short          s16x8 __attribute__((ext_vector_type(8)));
typedef unsigned short u16x4 __attribute__((ext_vector_type(4)));
typedef float          f32x4 __attribute__((ext_vector_type(4)));
typedef unsigned long long u64x2 __attribute__((ext_vector_type(2)));

// ---- module-scope device scratch (d_out is float32; d_ws unused) ----
__device__ __attribute__((aligned(16))) unsigned short g_hs[T_ * B_ * 2 * H_];  // [T][B][2H] bf16 bits
// 4-deep h exchange ring: [dir][buf(step&3)][B][H]; values class-tagged via bit14
__device__ __attribute__((aligned(16))) unsigned short g_hbuf[2 * 4 * B_ * H_];
__device__ __attribute__((aligned(16))) float    g_em[T_ * B_ * K_];            // [T][B][K] f32
__device__ __attribute__((aligned(16))) unsigned short g_wpk[2048 * 256];       // wih bf16 packed [f;b][256]
__device__ __attribute__((aligned(16))) unsigned short g_hpk[2048 * 256];       // whh bf16 packed [f;b][256]
// pre[t][n_tile(128)][m_tile(4)][lane(64)][4] f32 -- MFMA C-fragment layout (268 MB)
__device__ __attribute__((aligned(16))) float g_pre[(size_t)T_ * 128 * 4 * 64 * 4];
// ---- diagnostics: every failure mode -> distinct loss-slot value ----
__device__ int   g_marker;
__device__ int   g_done_pre;    // expect 512
__device__ int   g_done_lstm;   // expect 32
__device__ int   g_done_dec;    // expect 128
__device__ int   g_timeout;
__device__ float g_sum;

#define CLASS_MASK 0x4000400040004000ULL
#define RING_U64   (2 * 4 * B_ * H_ / 4)   // 32768 u64 sentinels

__device__ __forceinline__ f32x4 mfma16(s16x8 a, s16x8 b, f32x4 c) {
  return __builtin_amdgcn_mfma_f32_16x16x32_bf16(a, b, c, 0, 0, 0);
}

// f32 -> bf16 bits, round-to-nearest-even (finite inputs only)
__device__ __forceinline__ unsigned short f2b(float f) {
  unsigned u = __float_as_uint(f);
  u = (u + 0x7fffu + ((u >> 16) & 1u)) >> 16;
  return (unsigned short)u;
}

__device__ __forceinline__ s16x8 cvt8(const float* p) {
  s16x8 v;
#pragma unroll
  for (int j = 0; j < 8; ++j) v[j] = (short)f2b(p[j]);
  return v;
}

// assemble an MFMA A-fragment from two 64-bit raw words
__device__ __forceinline__ s16x8 frag2(unsigned long long a, unsigned long long b) {
  u64x2 t; t[0] = a; t[1] = b;
  return __builtin_bit_cast(s16x8, t);
}

// pre-fragment address for (time t, dir, slice s, wave wn/wm, lane, ni, mi)
__device__ __forceinline__ const f32x4* pre_tile(int t, int dir, int s, int wn, int wm,
                                                 int lane, int ni, int mi) {
  size_t idx = ((((size_t)t * 128 + dir * 64 + (2 * wn + ni) * 16 + s) * 4)
                + (wm * 2 + mi)) * 64 + lane;
  return (const f32x4*)(g_pre + idx * 4);
}

// ---------------- Kp: pack wih/whh to bf16 + init ring/diagnostics (merged k_zero) ----
__global__ __launch_bounds__(256) void k_prep(
    const float* __restrict__ wih_f, const float* __restrict__ wih_b,
    const float* __restrict__ whh_f, const float* __restrict__ whh_b) {
  const int r = blockIdx.x;     // 0..2047
  const int c = threadIdx.x;    // 0..255
  const int i = r * 256 + c;
  // init: ring sentinels (bit14=1 everywhere: class 1) + diagnostics, BOUNDED
  if (i < RING_U64) ((unsigned long long*)g_hbuf)[i] = CLASS_MASK;
  if (i == 0) {
    g_marker = 1;
    g_done_pre = 0;
    g_done_lstm = 0;
    g_done_dec = 0;
    g_timeout = 0;
    g_sum = 0.f;
  }
  const int rr = r & 1023;
  const float* wi = (r < 1024) ? wih_f : wih_b;
  const float* wh = (r < 1024) ? whh_f : whh_b;
  g_wpk[(size_t)r * 256 + c] = f2b(wi[(size_t)rr * E_ + c]);
  g_hpk[(size_t)r * 256 + c] = f2b(wh[(size_t)rr * H_ + c]);
}

// ---------------- Kq: input projection pre = xe @ wih^T, all t in parallel ----------
__global__ __launch_bounds__(256) void k_pre(const int* __restrict__ x,
                                             const float* __restrict__ emb) {
  const int t = blockIdx.x;
  const int tid = threadIdx.x;
  const int lane = tid & 63;
  const int wv = tid >> 6;
  const int wm = wv & 1;
  const int wn = wv >> 1;
  const int l15 = lane & 15;
  const int l4 = lane >> 4;
  const int b0 = wm * 32 + l15;
  const int b1 = b0 + 16;

  s16x8 a0[8], a1[8];
  {
    const float* e0 = emb + (size_t)x[b0 * T_ + t] * E_;
    const float* e1 = emb + (size_t)x[b1 * T_ + t] * E_;
#pragma unroll
    for (int kc = 0; kc < 8; ++kc) {
      a0[kc] = cvt8(e0 + kc * 32 + l4 * 8);
      a1[kc] = cvt8(e1 + kc * 32 + l4 * 8);
    }
  }

  for (int ntl = 0; ntl < 64; ++ntl) {
    const int nt = wn * 64 + ntl;      // n_tile 0..127 (f gates 0..63, b gates 64..127)
    s16x8 bf[8];
#pragma unroll
    for (int kc = 0; kc < 8; ++kc)
      bf[kc] = *(const s16x8*)(g_wpk + (size_t)(nt * 16 + l15) * 256 + kc * 32 + l4 * 8);
    f32x4 c0 = {0, 0, 0, 0}, c1 = {0, 0, 0, 0};
#pragma unroll
    for (int kc = 0; kc < 8; ++kc) {
      c0 = mfma16(a0[kc], bf[kc], c0);
      c1 = mfma16(a1[kc], bf[kc], c1);
    }
    *(f32x4*)(g_pre + ((((size_t)t * 128 + nt) * 4 + wm * 2 + 0) * 64 + lane) * 4) = c0;
    *(f32x4*)(g_pre + ((((size_t)t * 128 + nt) * 4 + wm * 2 + 1) * 64 + lane) * 4) = c1;
  }
  if (tid == 0) atomicAdd(&g_done_pre, 1);
}

// One LSTM time step with data-as-flag sync (verified R5 design). preC = acc-init;
// preN = next prefetch. G = this step's LDS exchange buffer (caller alternates).
__device__ __forceinline__ void lstm_step(
    int step, int dir, int s, int wv, int lane, int wm, int wn,
    int l15, int l4, int em_m, int em_jg,
    unsigned short* hb4,
    const s16x8 (&bfr)[2][8], const float (&bq)[4][4], float (&cst)[4],
    float* G, f32x4 (&preC)[4], f32x4 (&preN)[4])
{
  const int t = dir ? (T_ - 1 - step) : step;
  const int wbuf = step & 3;
  const int am0 = wm * 32 + l15;
  const int am1 = am0 + 16;
  const unsigned long long M = CLASS_MASK;

  // ---- observe: poll the h data itself; bit14 class == ((step-1)>>2)&1 => fresh ----
  unsigned long long r0[16], r1[16];
  if (step == 0) {
    // h_prev = 0: zero A-fragments (bit-identical to MFMA on a zeroed buffer)
#pragma unroll
    for (int i = 0; i < 16; ++i) { r0[i] = 0ull; r1[i] = 0ull; }
  } else {
    const int rbuf = (step - 1) & 3;
    const unsigned long long want = (((step - 1) >> 2) & 1) ? M : 0ull;
    const unsigned long long* hq = (const unsigned long long*)(hb4 + rbuf * (B_ * H_));
    const unsigned long long* h0q = hq + am0 * (H_ / 4) + l4 * 2;
    const unsigned long long* h1q = hq + am1 * (H_ / 4) + l4 * 2;
    int it = 0;
    for (;;) {
      unsigned long long bad = 0ull;
#pragma unroll
      for (int kc = 0; kc < 8; ++kc) {
        r0[2*kc]   = __hip_atomic_load(h0q + kc*8,   __ATOMIC_RELAXED, __HIP_MEMORY_SCOPE_AGENT);
        r0[2*kc+1] = __hip_atomic_load(h0q + kc*8+1, __ATOMIC_RELAXED, __HIP_MEMORY_SCOPE_AGENT);
        r1[2*kc]   = __hip_atomic_load(h1q + kc*8,   __ATOMIC_RELAXED, __HIP_MEMORY_SCOPE_AGENT);
        r1[2*kc+1] = __hip_atomic_load(h1q + kc*8+1, __ATOMIC_RELAXED, __HIP_MEMORY_SCOPE_AGENT);
      }
#pragma unroll
      for (int kc = 0; kc < 8; ++kc) {
        bad |= (r0[2*kc]   & M) ^ want;
        bad |= (r0[2*kc+1] & M) ^ want;
        bad |= (r1[2*kc]   & M) ^ want;
        bad |= (r1[2*kc+1] & M) ^ want;
      }
      if (__all(bad == 0ull)) break;
      __builtin_amdgcn_s_sleep(1);
      if (++it > (1 << 13)) { if (lane == 0) atomicAdd(&g_timeout, 1); break; }
    }
    if (want) {      // lossless decode: clear the class bit back out
#pragma unroll
      for (int i = 0; i < 16; ++i) { r0[i] ^= M; r1[i] ^= M; }
    }
  }

  // acc init = precomputed xe@wih^T partials; then h @ whh^T (same order as R4)
  f32x4 acc00 = preC[0], acc01 = preC[1], acc10 = preC[2], acc11 = preC[3];
#pragma unroll
  for (int kc = 0; kc < 8; ++kc) {
    s16x8 a0 = frag2(r0[2 * kc], r0[2 * kc + 1]);
    s16x8 a1 = frag2(r1[2 * kc], r1[2 * kc + 1]);
    acc00 = mfma16(a0, bfr[0][kc], acc00);
    acc01 = mfma16(a0, bfr[1][kc], acc01);
    acc10 = mfma16(a1, bfr[0][kc], acc10);
    acc11 = mfma16(a1, bfr[1][kc], acc11);
  }

  // scatter to LDS: G[m][n]; C/D layout col=lane&15, row=(lane>>4)*4+r
#pragma unroll
  for (int mi = 0; mi < 2; ++mi)
#pragma unroll
    for (int ni = 0; ni < 2; ++ni) {
      f32x4 a = (mi == 0) ? (ni == 0 ? acc00 : acc01) : (ni == 0 ? acc10 : acc11);
#pragma unroll
      for (int r = 0; r < 4; ++r) {
        int m = wm * 32 + mi * 16 + l4 * 4 + r;
        int n = (2 * wn + ni) * 16 + l15;
        G[m * 65 + n] = a[r];
      }
    }
  __syncthreads();   // the only per-step barrier (G is double-buffered by caller)

  // gates + state update
  unsigned short* hrow = hb4 + wbuf * (B_ * H_) + em_m * H_ + s * 16 + em_jg * 4;
  unsigned short* hsro = g_hs + ((size_t)t * B_ + em_m) * (2 * H_) + dir * H_ + s * 16 + em_jg * 4;
  u16x4 hv;
#pragma unroll
  for (int p = 0; p < 4; ++p) {
    int j = em_jg * 4 + p;
    float gi = G[em_m * 65 +  0 + j] + bq[0][p];
    float gf = G[em_m * 65 + 16 + j] + bq[1][p];
    float gg = G[em_m * 65 + 32 + j] + bq[2][p];
    float go = G[em_m * 65 + 48 + j] + bq[3][p];
    float ii = 1.f / (1.f + __expf(-gi));
    float ff = 1.f / (1.f + __expf(-gf));
    float gt = 1.f - 2.f / (__expf(2.f * gg) + 1.f);
    float oo = 1.f / (1.f + __expf(-go));
    float c = ff * cst[p] + ii * gt;
    cst[p] = c;
    float h = oo * (1.f - 2.f / (__expf(2.f * c) + 1.f));
    hv[p] = f2b(h);   // |h| < 1 (rounds at most to 1.0): bit14 always 0
  }
  // encode write-generation class into bit14; fire-and-forget (no drain, no flag)
  unsigned long long ev = __builtin_bit_cast(unsigned long long, hv);
  if ((step >> 2) & 1) ev ^= M;
  __hip_atomic_store((unsigned long long*)hrow, ev,
                     __ATOMIC_RELAXED, __HIP_MEMORY_SCOPE_AGENT);

  // off critical path: persistent h store + pre-fragment prefetch for step+1
  // (prefetch at step END -- drains inside the next poll window; R6 proved
  //  early placement regresses)
  *(u16x4*)hsro = hv;
  if (step + 1 < T_) {
    const int tn = dir ? (T_ - 2 - step) : (step + 1);
    preN[0] = *pre_tile(tn, dir, s, wn, wm, lane, 0, 0);
    preN[1] = *pre_tile(tn, dir, s, wn, wm, lane, 1, 0);
    preN[2] = *pre_tile(tn, dir, s, wn, wm, lane, 0, 1);
    preN[3] = *pre_tile(tn, dir, s, wn, wm, lane, 1, 1);
  }
}

// ---------------- K1: biLSTM recurrence (h @ whh^T only; pre from g_pre) ----------
// 32 WGs: dir = wg&1, slice s = wg>>1. 4 waves. Data-as-flag sync: one MALL round
// trip per step (producer encoded store -> consumer validating load). 4-buffer ring
// is deadlock-free: storing step w requires all step-w-1 data, which implies every
// WG's position >= w, so nobody still reads the w-4 data being overwritten.
__global__ __launch_bounds__(256, 1) void k_lstm(
    const float* __restrict__ b_f, const float* __restrict__ b_b)
{
  const int wg  = blockIdx.x;
  const int dir = wg & 1;
  const int s   = wg >> 1;
  const int tid = threadIdx.x;
  const int lane = tid & 63;
  const int wv  = tid >> 6;      // 0..3
  const int wm  = wv & 1;        // M half (batches wm*32..+31)
  const int wn  = wv >> 1;       // N half (gate-rows wn*32..+31)
  const int l15 = lane & 15;
  const int l4  = lane >> 4;

  const float* bias = dir ? b_b : b_f;
  unsigned short* hb4 = g_hbuf + (size_t)dir * (4 * B_ * H_);

  // stationary whh B-fragments from packed bf16: K = 256 (h only)
  s16x8 bfr[2][8];
#pragma unroll
  for (int ni = 0; ni < 2; ++ni) {
    const int nt = dir * 64 + (2 * wn + ni) * 16 + s;     // global n_tile
    const unsigned short* wr = g_hpk + (size_t)(nt * 16 + l15) * 256;
#pragma unroll
    for (int kc = 0; kc < 8; ++kc)
      bfr[ni][kc] = *(const s16x8*)(wr + kc * 32 + l4 * 8);
  }

  // epilogue mapping: thread -> (batch em_m, 4 units em_jg*4..+3)
  const int em_m  = tid >> 2;
  const int em_jg = tid & 3;
  float bq[4][4];
#pragma unroll
  for (int q = 0; q < 4; ++q)
#pragma unroll
    for (int p = 0; p < 4; ++p) bq[q][p] = bias[q * H_ + s * 16 + em_jg * 4 + p];
  float cst[4] = {0.f, 0.f, 0.f, 0.f};

  __shared__ float Ga[64 * 65];
  __shared__ float Gb[64 * 65];

  // prologue: pre fragments for step 0 into buffer A
  f32x4 preA[4], preB[4];
  {
    const int t0 = dir ? (T_ - 1) : 0;
    preA[0] = *pre_tile(t0, dir, s, wn, wm, lane, 0, 0);
    preA[1] = *pre_tile(t0, dir, s, wn, wm, lane, 1, 0);
    preA[2] = *pre_tile(t0, dir, s, wn, wm, lane, 0, 1);
    preA[3] = *pre_tile(t0, dir, s, wn, wm, lane, 1, 1);
  }

  // T_ = 512 even: explicit 2-step unroll keeps pre buffers + G statically named
  for (int sp = 0; sp < T_; sp += 2) {
    lstm_step(sp,     dir, s, wv, lane, wm, wn, l15, l4, em_m, em_jg,
              hb4, bfr, bq, cst, Ga, preA, preB);
    lstm_step(sp + 1, dir, s, wv, lane, wm, wn, l15, l4, em_m, em_jg,
              hb4, bfr, bq, cst, Gb, preB, preA);
  }

  __syncthreads();
  if (tid == 0) atomicAdd(&g_done_lstm, 1);
}

// ---------------- K2: emissions em[t][b][k] = hs @ wc^T + bc (MFMA, N padded to 32) ----
__global__ __launch_bounds__(256) void k_em(const float* __restrict__ wc,
                                            const float* __restrict__ bc) {
  const int tid = threadIdx.x;
  const int lane = tid & 63;
  const int wv = tid >> 6;
  const int l15 = lane & 15;
  const int l4 = lane >> 4;
  const int row0 = blockIdx.x * 64 + wv * 16;   // (t*64+b) row block

  s16x8 bfr[2][16];
#pragma unroll
  for (int ni = 0; ni < 2; ++ni) {
    int n = ni * 16 + l15;
#pragma unroll
    for (int kc = 0; kc < 16; ++kc) {
      s16x8 v;
      if (n < K_) {
        v = cvt8(wc + (size_t)n * (2 * H_) + kc * 32 + l4 * 8);
      } else {
#pragma unroll
        for (int jj = 0; jj < 8; ++jj) v[jj] = 0;
      }
      bfr[ni][kc] = v;
    }
  }

  f32x4 acc0 = {0,0,0,0}, acc1 = {0,0,0,0};
  const unsigned short* arow = g_hs + (size_t)(row0 + l15) * (2 * H_) + l4 * 8;
#pragma unroll
  for (int kc = 0; kc < 16; ++kc) {
    s16x8 a = *(const s16x8*)(arow + kc * 32);
    acc0 = mfma16(a, bfr[0][kc], acc0);
    acc1 = mfma16(a, bfr[1][kc], acc1);
  }
#pragma unroll
  for (int r = 0; r < 4; ++r) {
    int m = l4 * 4 + r;
    g_em[(size_t)(row0 + m) * K_ + l15] = acc0[r] + bc[l15];       // n0 = l15 < 16 < K
    int n1 = 16 + l15;
    if (n1 < K_) g_em[(size_t)(row0 + m) * K_ + n1] = acc1[r] + bc[n1];
  }
}

// ---------------- K3: decode. blocks 0..63: Viterbi tags; 64..127: CRF llh ----------------
__global__ void k_decode(const int* __restrict__ y,
                         const float* __restrict__ start, const float* __restrict__ endw,
                         const float* __restrict__ trans,
                         float* __restrict__ out_tags) {
  const int id = blockIdx.x;
  const int k = threadIdx.x;   // 64 threads = 1 wave
  const float* em = g_em;
  __shared__ float tr[K_ * K_];
  __shared__ float sc[K_];
  __shared__ unsigned char bp[T_][K_];
  __shared__ short tags[T_];
  __shared__ float zsh;

  for (int i = k; i < K_ * K_; i += 64) tr[i] = trans[i];
  __syncthreads();

  if (id < B_) {
    // ---- Viterbi (argmax ties -> first index, matching jnp.argmax) ----
    const int b = id;
    float score = 0.f;
    if (k < K_) score = start[k] + em[(size_t)b * K_ + k];
    __syncthreads();
    for (int t = 1; t < T_; ++t) {
      if (k < K_) sc[k] = score;
      __syncthreads();
      if (k < K_) {
        float e = em[(size_t)(t * B_ + b) * K_ + k];
        float best = -1e30f; int bi = 0;
        for (int k1 = 0; k1 < K_; ++k1) {
          float v = sc[k1] + tr[k1 * K_ + k];
          if (v > best) { best = v; bi = k1; }
        }
        score = best + e;
        bp[t][k] = (unsigned char)bi;
      }
      __syncthreads();
    }
    if (k < K_) sc[k] = score + endw[k];
    __syncthreads();
    if (k == 0) {
      float best = -1e30f; int bi = 0;
      for (int k1 = 0; k1 < K_; ++k1) if (sc[k1] > best) { best = sc[k1]; bi = k1; }
      short tag = (short)bi;
      tags[T_ - 1] = tag;
      for (int t = T_ - 1; t > 0; --t) { tag = (short)bp[t][tag]; tags[t - 1] = tag; }
    }
    __syncthreads();
    // OUTPUT IS FLOAT32 (reference outputs are int32/f32, not bf16)
    for (int t = k; t < T_; t += 64) out_tags[(size_t)b * T_ + t] = (float)tags[t];
    __syncthreads();
    if (k == 0) atomicAdd(&g_done_dec, 1);
  } else {
    // ---- CRF log-likelihood ----
    const int b = id - B_;
    float al = 0.f;
    if (k < K_) al = start[k] + em[(size_t)b * K_ + k];
    __syncthreads();
    for (int t = 1; t < T_; ++t) {
      if (k < K_) sc[k] = al;
      __syncthreads();
      if (k < K_) {
        float e = em[(size_t)(t * B_ + b) * K_ + k];
        float m = -1e30f;
        for (int k1 = 0; k1 < K_; ++k1) m = fmaxf(m, sc[k1] + tr[k1 * K_ + k]);
        float ssum = 0.f;
        for (int k1 = 0; k1 < K_; ++k1) ssum += __expf(sc[k1] + tr[k1 * K_ + k] - m);
        al = m + __logf(ssum) + e;
      }
      __syncthreads();
    }
    if (k < K_) sc[k] = al + endw[k];
    __syncthreads();
    if (k == 0) {
      float m = -1e30f;
      for (int k1 = 0; k1 < K_; ++k1) m = fmaxf(m, sc[k1]);
      float ssum = 0.f;
      for (int k1 = 0; k1 < K_; ++k1) ssum += __expf(sc[k1] - m);
      zsh = m + __logf(ssum);
    }
    __syncthreads();
    const int* yb = y + b * T_;
    float local = 0.f;
    for (int t = k; t < T_; t += 64) {
      if (t >= 1) {
        int y1 = yb[t], y0 = yb[t - 1];
        local += tr[y0 * K_ + y1] + em[(size_t)(t * B_ + b) * K_ + y1];
      }
    }
    for (int off = 32; off > 0; off >>= 1) local += __shfl_down(local, off, 64);
    if (k == 0) {
      int y0 = yb[0], yl = yb[T_ - 1];
      float num = local + start[y0] + em[(size_t)b * K_ + y0] + endw[yl];
      atomicAdd(&g_sum, (num - zsh) * (1.0f / 64.0f));
      atomicAdd(&g_done_dec, 1);
    }
  }
}

// ---------------- K4: finalize; encode pipeline state into the float loss slot ----------
// error map (vs ref ~ -1560): pass | -2600=timeout | -2800=sum~0 | -3000-32d=lstm
// incomplete | -6000-32d=decode incomplete | -9000-d=pre incomplete | -20000=init missing
__global__ void k_fin(float* __restrict__ out) {
  float v;
  if (g_marker != 1)             v = -20000.f;
  else if (g_done_pre < 512)     v = -9000.f - (float)g_done_pre;
  else if (g_done_lstm < 32)     v = -3000.f - 32.f * (float)g_done_lstm;
  else if (g_done_dec < 128)     v = -6000.f - 32.f * (float)g_done_dec;
  else if (g_timeout != 0)       v = -2600.f;
  else if (fabsf(g_sum) <= 0.5f) v = -2800.f;
  else                           v = g_sum;
  out[0] = v;
}

extern "C" void kernel_launch(void* const* d_in, const int* in_sizes, int n_in,
                              void* d_out, int out_size, void* d_ws, size_t ws_size,
                              hipStream_t stream) {
  const int*   x     = (const int*)d_in[0];
  const int*   y     = (const int*)d_in[1];
  // d_in[2] = masks: all-true by construction -> unused
  const float* emb   = (const float*)d_in[3];
  const float* wih_f = (const float*)d_in[4];
  const float* whh_f = (const float*)d_in[5];
  const float* b_f   = (const float*)d_in[6];
  const float* wih_b = (const float*)d_in[7];
  const float* whh_b = (const float*)d_in[8];
  const float* b_b   = (const float*)d_in[9];
  const float* wc    = (const float*)d_in[10];
  const float* bc    = (const float*)d_in[11];
  const float* start = (const float*)d_in[12];
  const float* endw  = (const float*)d_in[13];
  const float* trans = (const float*)d_in[14];

  float* out_f = (float*)d_out;   // float32: tags [0..B*T), loss at [B*T]

  k_prep<<<2048, 256, 0, stream>>>(wih_f, wih_b, whh_f, whh_b);   // also inits ring+diag
  k_pre<<<T_, 256, 0, stream>>>(x, emb);
  k_lstm<<<32, 256, 0, stream>>>(b_f, b_b);
  k_em<<<(T_ * B_) / 64, 256, 0, stream>>>(wc, bc);
  k_decode<<<128, 64, 0, stream>>>(y, start, endw, trans, out_f);
  k_fin<<<1, 1, 0, stream>>>(out_f + (size_t)B_ * T_);
}